// Round 11
// baseline (139.655 us; speedup 1.0000x reference)
//
#include <hip/hip_runtime.h>

// B=32, F=node=128, T=2048, HID=256, NC=64, A=15 windows
// k_prep: W1T/W2T/W3T + xT (R5 shape). k_xw1: 64-block GEMM. k_chain: R10 +
// global-operand prefetch (op1 B nt+1, op2 A ks+1, op4 A hoisted).

typedef float f32x4 __attribute__((ext_vector_type(4)));
typedef __bf16 bf16x8 __attribute__((ext_vector_type(8)));
typedef unsigned short u16x4 __attribute__((ext_vector_type(4)));
typedef unsigned short u16x8 __attribute__((ext_vector_type(8)));

__device__ inline unsigned short f2b(float f) {
  unsigned int u = __float_as_uint(f);
  unsigned int r = u + 0x7fffu + ((u >> 16) & 1u);
  return (unsigned short)(r >> 16);
}
__device__ inline float leaky(float v) { return v >= 0.f ? v : 0.2f * v; }

#define SWZ(k, r) ((k) ^ (((r) & 7) << 3))

// ---------------- k_prep: W transposes (bid<148) + x transpose (bid>=148) ----
__global__ __launch_bounds__(256) void k_prep(const float* __restrict__ x,
                                              const float* __restrict__ W1,
                                              const float* __restrict__ W2,
                                              const float* __restrict__ W3,
                                              unsigned short* __restrict__ W1T,
                                              unsigned short* __restrict__ W2T,
                                              unsigned short* __restrict__ W3T,
                                              unsigned short* __restrict__ xT) {
  __shared__ float t[64][65];
  const int bid = blockIdx.x;
  const int tid = threadIdx.x;
  if (bid < 148) {
    const float* src;
    unsigned short* dst;
    int K, N, k0, n0;
    if (bid < 128) {        // W1 [2048][256] -> W1T [256][2048]
      src = W1; dst = W1T; K = 2048; N = 256;
      k0 = (bid >> 2) * 64; n0 = (bid & 3) * 64;
    } else if (bid < 144) { // W2 [256][256] -> W2T [256][256]
      src = W2; dst = W2T; K = 256; N = 256;
      int i = bid - 128; k0 = (i >> 2) * 64; n0 = (i & 3) * 64;
    } else {                // W3 [256][64] -> W3T [64][256]
      src = W3; dst = W3T; K = 256; N = 64;
      int i = bid - 144; k0 = i * 64; n0 = 0;
    }
#pragma unroll
    for (int it = 0; it < 16; ++it) {
      int e = tid + it * 256, r = e >> 6, c = e & 63;
      t[r][c] = src[(size_t)(k0 + r) * N + n0 + c];
    }
    __syncthreads();
#pragma unroll
    for (int it = 0; it < 16; ++it) {
      int e = tid + it * 256, rr = e >> 6, cc = e & 63;
      dst[(size_t)(n0 + rr) * K + k0 + cc] = f2b(t[cc][rr]);
    }
  } else {
    // x [32][128][2048] fp32 -> xT [32][2048][128] bf16, 64x64 tiles
    int idx = bid - 148;               // 0..2047
    int b = idx >> 6, rem = idx & 63;
    int tt = rem >> 1, ft = rem & 1;
    int t0 = tt * 64, f0 = ft * 64;
    const float* xb = x + ((size_t)b * 128 + f0) * 2048 + t0;
#pragma unroll
    for (int it = 0; it < 16; ++it) {
      int e = tid + it * 256, r = e >> 6, c = e & 63;   // r=f-rel, c=t-rel
      t[r][c] = xb[(size_t)r * 2048 + c];
    }
    __syncthreads();
    unsigned short* dst = xT + ((size_t)b * 2048 + t0) * 128 + f0;
#pragma unroll
    for (int it = 0; it < 4; ++it) {
      int e = tid + it * 256, rr = e >> 4, c4 = (e & 15) * 4;  // rr=t-rel, c4=f-rel
      u16x4 s;
#pragma unroll
      for (int q = 0; q < 4; ++q) s[q] = f2b(t[c4 + q][rr]);
      *(u16x4*)&dst[rr * 128 + c4] = s;
    }
  }
}

// ---------------- k_xw1: XW1T[b][hid 256][f-half 64], 64 blocks ----------------
__global__ __launch_bounds__(512) void k_xw1(const float* __restrict__ x,
                                             const unsigned short* __restrict__ W1T,
                                             unsigned short* __restrict__ XW1T) {
  __shared__ __align__(16) unsigned short sX[2][64 * 64];
  const int bid = blockIdx.x;
  const int tid = threadIdx.x;
  const int b = bid >> 1, f0 = (bid & 1) * 64;
  const int w = tid >> 6, lane = tid & 63;
  const int l15 = lane & 15, l4 = lane >> 4;
  const float* xb = x + ((size_t)b * 128 + f0) * 2048;
  const int fr = tid >> 3, k8 = (tid & 7) * 8;
  f32x4 xr0, xr1;
  f32x4 acc[2][4] = {};

  auto LOADX = [&](int kb) {
    xr0 = *(const f32x4*)&xb[(size_t)fr * 2048 + kb * 64 + k8];
    xr1 = *(const f32x4*)&xb[(size_t)fr * 2048 + kb * 64 + k8 + 4];
  };
  auto STOREX = [&](int buf) {
    u16x8 s;
#pragma unroll
    for (int q = 0; q < 8; ++q) s[q] = f2b(q < 4 ? xr0[q] : xr1[q - 4]);
    *(u16x8*)&sX[buf][fr * 64 + SWZ(k8, fr)] = s;
  };

  LOADX(0);
  STOREX(0);
  __syncthreads();
  for (int kb = 0; kb < 32; ++kb) {
    if (kb < 31) LOADX(kb + 1);
    const int buf = kb & 1;
#pragma unroll
    for (int ks = 0; ks < 2; ++ks) {
      bf16x8 af[2];
#pragma unroll
      for (int mt = 0; mt < 2; ++mt)
        af[mt] = *(const bf16x8*)&W1T[(size_t)(w * 32 + mt * 16 + l15) * 2048 + kb * 64 + ks * 32 + l4 * 8];
#pragma unroll
      for (int nt = 0; nt < 4; ++nt) {
        int br = nt * 16 + l15;
        bf16x8 bf = *(const bf16x8*)&sX[buf][br * 64 + SWZ(ks * 32 + l4 * 8, br)];
#pragma unroll
        for (int mt = 0; mt < 2; ++mt)
          acc[mt][nt] = __builtin_amdgcn_mfma_f32_16x16x32_bf16(af[mt], bf, acc[mt][nt], 0, 0, 0);
      }
    }
    if (kb < 31) {
      STOREX(buf ^ 1);
      __syncthreads();
    }
  }
#pragma unroll
  for (int mt = 0; mt < 2; ++mt)
#pragma unroll
    for (int nt = 0; nt < 4; ++nt)
#pragma unroll
      for (int r = 0; r < 4; ++r) {
        int p = w * 32 + mt * 16 + l4 * 4 + r;
        XW1T[((size_t)b * 256 + p) * 128 + f0 + nt * 16 + l15] = f2b(acc[mt][nt][r]);
      }
}

// ---------------- k_chain: compact chain + global-operand prefetch ----------------
__global__ __launch_bounds__(512) void k_chain(
    const unsigned short* __restrict__ xT, const unsigned short* __restrict__ XW1T,
    const unsigned short* __restrict__ W2T, const unsigned short* __restrict__ W3T,
    const float* __restrict__ b1g, const float* __restrict__ b2g,
    const float* __restrict__ b3g, float* __restrict__ gXa) {
  __shared__ __align__(16) unsigned short R0[128 * 128];
  __shared__ __align__(16) unsigned short R1[128 * 128];
  __shared__ float fS[256];

  const int tid = threadIdx.x;
  const int w = tid >> 6, lane = tid & 63;
  const int l15 = lane & 15, l4 = lane >> 4;
  const int ridx = (blockIdx.x & 7) * 60 + (blockIdx.x >> 3);
  const int b = ridx / 15, a = ridx % 15;
  const int m0 = w * 16;
  const unsigned short* XWb = XW1T + (size_t)b * 256 * 128;
  const float inv128 = 1.f / 128.f;

  // ---- P0: win[node j][f] <- xT into R1 ----
  const unsigned short* src = xT + ((size_t)b * 2048 + (size_t)a * 128) * 128;
#pragma unroll 1
  for (int it = 0; it < 4; ++it) {
    int tt = tid + it * 512;
    int j = tt >> 4, f8 = (tt & 15) * 8;
    *(u16x8*)&R1[j * 128 + SWZ(f8, j)] = *(const u16x8*)&src[j * 128 + f8];
  }
  __syncthreads();  // B0

  // ---- syrk prologue: A-frags, row sums (ones-MFMA), own diag (self-MFMA) ----
  bf16x8 afw[4];
#pragma unroll
  for (int ks = 0; ks < 4; ++ks) {
    int ar = m0 + l15;
    afw[ks] = *(const bf16x8*)&R1[ar * 128 + SWZ(ks * 32 + l4 * 8, ar)];
  }
  bf16x8 ones;
#pragma unroll
  for (int q = 0; q < 8; ++q) ones[q] = (__bf16)1.0f;
  f32x4 sacc = {}, dacc = {};
#pragma unroll
  for (int ks = 0; ks < 4; ++ks) {
    sacc = __builtin_amdgcn_mfma_f32_16x16x32_bf16(afw[ks], ones, sacc, 0, 0, 0);
    dacc = __builtin_amdgcn_mfma_f32_16x16x32_bf16(afw[ks], afw[ks], dacc, 0, 0, 0);
  }
#pragma unroll
  for (int r = 0; r < 4; ++r) {
    if (l15 == 0) fS[m0 + l4 * 4 + r] = sacc[r];
    if (l15 == l4 * 4 + r)
      fS[128 + m0 + l4 * 4 + r] = dacc[r] - sacc[r] * sacc[r] * inv128;
  }
  __syncthreads();  // B1: sums + diag visible

  // ---- syrk main: one-pass center/scale/clip -> adj bf16 in R0 ----
  float div[4];
#pragma unroll
  for (int r = 0; r < 4; ++r) {
    float d = fS[128 + m0 + l4 * 4 + r];
    div[r] = d > 0.f ? __frsqrt_rn(d) : 0.f;
  }
#pragma unroll 1
  for (int nt = 0; nt < 8; ++nt) {
    int col = nt * 16 + l15;
    f32x4 c = {};
#pragma unroll
    for (int ks = 0; ks < 4; ++ks) {
      bf16x8 bf = *(const bf16x8*)&R1[col * 128 + SWZ(ks * 32 + l4 * 8, col)];
      c = __builtin_amdgcn_mfma_f32_16x16x32_bf16(afw[ks], bf, c, 0, 0, 0);
    }
    float fc = fS[col];
    float dc = fS[128 + col];
    float djv = dc > 0.f ? __frsqrt_rn(dc) : 0.f;
#pragma unroll
    for (int r = 0; r < 4; ++r) {
      float v = (c[r] - sacc[r] * fc * inv128) * div[r] * djv;
      v = fminf(1.f, fmaxf(-1.f, v));
      v = 0.5f * v + 0.5f;
      if (div[r] == 0.f || djv == 0.f) v = 0.f;  // nan_to_num
      int row = m0 + l4 * 4 + r;
      R0[row * 128 + SWZ(col, row)] = f2b(v);
    }
  }
  bf16x8 afj[4];
#pragma unroll
  for (int ks = 0; ks < 4; ++ks)
    afj[ks] = *(const bf16x8*)&R0[(m0 + l15) * 128 + SWZ(ks * 32 + l4 * 8, m0 + l15)];
  __syncthreads();  // B2: win reads + afj loads done

  // ---- op1: h1 = leaky(adj @ XW1b + b1); B prefetched 1 nt ahead ----
#pragma unroll 1
  for (int half = 0; half < 2; ++half) {
    unsigned short* Rd = half ? R0 : R1;
    const unsigned short* Bbase = &XWb[(size_t)half * 128 * 128 + l4 * 8];
    bf16x8 bpf[4];
#pragma unroll
    for (int ks = 0; ks < 4; ++ks)
      bpf[ks] = *(const bf16x8*)&Bbase[(size_t)l15 * 128 + ks * 32];
#pragma unroll 1
    for (int nt = 0; nt < 8; ++nt) {
      bf16x8 bc[4];
#pragma unroll
      for (int ks = 0; ks < 4; ++ks) bc[ks] = bpf[ks];
      if (nt < 7) {
#pragma unroll
        for (int ks = 0; ks < 4; ++ks)
          bpf[ks] = *(const bf16x8*)&Bbase[(size_t)((nt + 1) * 16 + l15) * 128 + ks * 32];
      }
      f32x4 acc = {};
#pragma unroll
      for (int ks = 0; ks < 4; ++ks)
        acc = __builtin_amdgcn_mfma_f32_16x16x32_bf16(afj[ks], bc[ks], acc, 0, 0, 0);
      float bias = b1g[half * 128 + nt * 16 + l15];
#pragma unroll
      for (int r = 0; r < 4; ++r) {
        int row = m0 + l4 * 4 + r;
        Rd[row * 128 + SWZ(nt * 16 + l15, row)] = f2b(leaky(acc[r] + bias));
      }
    }
  }
  __syncthreads();  // B3: h1 complete

  // ---- op2: u2T = W2T @ h1^T, K=256; A prefetched 1 ks ahead ----
  f32x4 u2[2][8] = {};
  {
    const unsigned short* A0 = &W2T[(size_t)(w * 32 + l15) * 256 + l4 * 8];
    const unsigned short* A1 = &W2T[(size_t)(w * 32 + 16 + l15) * 256 + l4 * 8];
    bf16x8 a0p = *(const bf16x8*)&A0[0];
    bf16x8 a1p = *(const bf16x8*)&A1[0];
#pragma unroll 1
    for (int ks = 0; ks < 8; ++ks) {
      bf16x8 a0 = a0p, a1 = a1p;
      if (ks < 7) {
        a0p = *(const bf16x8*)&A0[(ks + 1) * 32];
        a1p = *(const bf16x8*)&A1[(ks + 1) * 32];
      }
      const unsigned short* Rs = (ks < 4) ? R1 : R0;
      int kk = (ks & 3) * 32 + l4 * 8;
#pragma unroll
      for (int nt = 0; nt < 8; ++nt) {
        int br = nt * 16 + l15;
        bf16x8 bf = *(const bf16x8*)&Rs[br * 128 + SWZ(kk, br)];
        u2[0][nt] = __builtin_amdgcn_mfma_f32_16x16x32_bf16(a0, bf, u2[0][nt], 0, 0, 0);
        u2[1][nt] = __builtin_amdgcn_mfma_f32_16x16x32_bf16(a1, bf, u2[1][nt], 0, 0, 0);
      }
    }
  }
  __syncthreads();  // B4: all h1 reads done

#pragma unroll
  for (int mt = 0; mt < 2; ++mt)
#pragma unroll
    for (int nt = 0; nt < 8; ++nt)
#pragma unroll
      for (int r = 0; r < 4; ++r) {
        int grow = w * 32 + mt * 16 + l4 * 4 + r;
        int col = nt * 16 + l15;
        unsigned short* Rd = (grow < 128) ? R0 : R1;
        int lr = grow & 127;
        Rd[lr * 128 + SWZ(col, lr)] = f2b(u2[mt][nt][r]);
      }
  __syncthreads();  // B5: u2T stored

  // ---- op3: h2 = leaky(adj @ u2 + b2), full hid 256 ----
  f32x4 h2acc[16];
#pragma unroll
  for (int nt = 0; nt < 16; ++nt) h2acc[nt] = f32x4{0.f, 0.f, 0.f, 0.f};
#pragma unroll
  for (int ks = 0; ks < 4; ++ks)
#pragma unroll
    for (int nt = 0; nt < 16; ++nt) {
      int brl = (nt & 7) * 16 + l15;
      const unsigned short* Rs = (nt < 8) ? R0 : R1;
      bf16x8 bf = *(const bf16x8*)&Rs[brl * 128 + SWZ(ks * 32 + l4 * 8, brl)];
      h2acc[nt] = __builtin_amdgcn_mfma_f32_16x16x32_bf16(afj[ks], bf, h2acc[nt], 0, 0, 0);
    }
  __syncthreads();  // B6: all u2T reads done

#pragma unroll
  for (int nt = 0; nt < 16; ++nt) {
    float bias = b2g[nt * 16 + l15];
#pragma unroll
    for (int r = 0; r < 4; ++r) {
      int row = m0 + l4 * 4 + r;
      int coll = (nt & 7) * 16 + l15;
      unsigned short* Rd = (nt < 8) ? R0 : R1;
      Rd[row * 128 + SWZ(coll, row)] = f2b(leaky(h2acc[nt][r] + bias));
    }
  }
  // ---- hoist op4 A-frags (W3T) here: latency hides under B7 + op4 B-reads ----
  const int mrow = (w >> 1) * 16, ntb = (w & 1) * 4;
  bf16x8 a3f[8];
#pragma unroll
  for (int ks = 0; ks < 8; ++ks)
    a3f[ks] = *(const bf16x8*)&W3T[(size_t)(mrow + l15) * 256 + ks * 32 + l4 * 8];
  __syncthreads();  // B7: h2 stored

  // ---- op4: u3T = W3T @ h2^T, K=256 (R0 then R1) ----
  f32x4 u3[4] = {};
#pragma unroll
  for (int kh = 0; kh < 2; ++kh) {
    const unsigned short* Rs = kh ? R1 : R0;
#pragma unroll
    for (int ks = 0; ks < 4; ++ks) {
#pragma unroll
      for (int nti = 0; nti < 4; ++nti) {
        int br = (ntb + nti) * 16 + l15;
        bf16x8 bf = *(const bf16x8*)&Rs[br * 128 + SWZ(ks * 32 + l4 * 8, br)];
        u3[nti] = __builtin_amdgcn_mfma_f32_16x16x32_bf16(a3f[kh * 4 + ks], bf, u3[nti], 0, 0, 0);
      }
    }
  }
  __syncthreads();  // B8: all h2 reads done

#pragma unroll
  for (int nti = 0; nti < 4; ++nti)
#pragma unroll
    for (int r = 0; r < 4; ++r) {
      int grow = mrow + l4 * 4 + r;
      int col = (ntb + nti) * 16 + l15;
      R0[grow * 128 + SWZ(col, grow)] = f2b(u3[nti][r]);
    }
  __syncthreads();  // B9: u3T stored

  // ---- op5: xa = leaky(adj @ u3 + b3); mean over node via shuffles ----
  {
    float* pf = reinterpret_cast<float*>(R1);
#pragma unroll 1
    for (int nt = 0; nt < 4; ++nt) {
      f32x4 acc = {};
      int br = nt * 16 + l15;
#pragma unroll
      for (int ks = 0; ks < 4; ++ks) {
        bf16x8 bf = *(const bf16x8*)&R0[br * 128 + SWZ(ks * 32 + l4 * 8, br)];
        acc = __builtin_amdgcn_mfma_f32_16x16x32_bf16(afj[ks], bf, acc, 0, 0, 0);
      }
      float bias = b3g[br];
      float v = 0.f;
#pragma unroll
      for (int r = 0; r < 4; ++r) v += leaky(acc[r] + bias);
      v += __shfl_xor(v, 16);
      v += __shfl_xor(v, 32);
      if (l4 == 0) pf[w * 64 + br] = v;
    }
  }
  __syncthreads();  // B10
  if (tid < 64) {
    const float* pf = reinterpret_cast<const float*>(R1);
    float s = 0.f;
#pragma unroll
    for (int gg = 0; gg < 8; ++gg) s += pf[gg * 64 + tid];
    gXa[((size_t)b * 15 + a) * 64 + tid] = s * (1.f / 128.f);
  }
}

// ---------------- k_head: per-batch head ----------------
__global__ __launch_bounds__(256) void k_head(const float* __restrict__ gXa,
                                              const float* __restrict__ W4,
                                              const float* __restrict__ b4,
                                              float* __restrict__ out) {
  __shared__ float xb[15 * 64];
  __shared__ float c2[15 * 16];
  __shared__ float mu[15];
  __shared__ float dinv[15];
  __shared__ float yy[15 * 64];
  __shared__ float zz[15 * 64];
  const int b = blockIdx.x;
  const int tid = threadIdx.x;
  for (int e = tid; e < 960; e += 256) xb[e] = gXa[(size_t)b * 960 + e];
  __syncthreads();
  if (tid < 15) {
    float s = 0.f;
    for (int c = 0; c < 64; ++c) s += xb[tid * 64 + c];
    mu[tid] = s * (1.f / 64.f);
  }
  __syncthreads();
  if (tid < 225) {
    int p = tid / 15, q = tid % 15;
    float s = 0.f;
    for (int c = 0; c < 64; ++c)
      s += (xb[p * 64 + c] - mu[p]) * (xb[q * 64 + c] - mu[q]);
    c2[p * 16 + q] = s;
  }
  __syncthreads();
  if (tid < 15) {
    float d = c2[tid * 16 + tid];
    dinv[tid] = d > 0.f ? (1.f / sqrtf(d)) : 0.f;
  }
  __syncthreads();
  if (tid < 225) {
    int p = tid / 15, q = tid % 15;
    float v = c2[p * 16 + q] * dinv[p] * dinv[q];
    v = fminf(1.f, fmaxf(-1.f, v));
    if (dinv[p] == 0.f || dinv[q] == 0.f) v = 0.f;
    c2[p * 16 + q] = v;
  }
  __syncthreads();
  for (int e = tid; e < 960; e += 256) {
    int p = e >> 6, c = e & 63;
    float s = 0.f;
    for (int q = 0; q < 15; ++q) s += c2[p * 16 + q] * xb[q * 64 + c];
    yy[e] = s;
  }
  __syncthreads();
  for (int e = tid; e < 960; e += 256) {
    int p = e >> 6, c = e & 63;
    float s = b4[c];
    for (int k = 0; k < 64; ++k) s += yy[p * 64 + k] * W4[k * 64 + c];
    zz[e] = leaky(s);
  }
  __syncthreads();
  if (tid < 64) {
    float m = -INFINITY;
    for (int p = 0; p < 15; ++p) m = fmaxf(m, zz[p * 64 + tid]);
    out[(size_t)b * 64 + tid] = m;
  }
}

extern "C" void kernel_launch(void* const* d_in, const int* in_sizes, int n_in,
                              void* d_out, int out_size, void* d_ws, size_t ws_size,
                              hipStream_t stream) {
  const float* x  = (const float*)d_in[0];
  const float* W1 = (const float*)d_in[1];
  const float* b1 = (const float*)d_in[2];
  const float* W2 = (const float*)d_in[3];
  const float* b2 = (const float*)d_in[4];
  const float* W3 = (const float*)d_in[5];
  const float* b3 = (const float*)d_in[6];
  const float* W4 = (const float*)d_in[7];
  const float* b4 = (const float*)d_in[8];
  float* out = (float*)d_out;

  char* ws = (char*)d_ws;
  unsigned short* xT   = (unsigned short*)ws;                 // 16 MB
  unsigned short* XW1T = (unsigned short*)(ws + 16777216);    // 2 MB
  unsigned short* W1T  = (unsigned short*)(ws + 18874368);    // 1 MB
  unsigned short* W2T  = (unsigned short*)(ws + 19922944);    // 128 KB
  unsigned short* W3T  = (unsigned short*)(ws + 20054016);    // 32 KB
  float* gXa           = (float*)(ws + 20086784);             // 120 KB

  k_prep<<<2196, 256, 0, stream>>>(x, W1, W2, W3, W1T, W2T, W3T, xT);
  k_xw1<<<64, 512, 0, stream>>>(x, W1T, XW1T);
  k_chain<<<480, 512, 0, stream>>>(xT, XW1T, W2T, W3T, b1, b2, b3, gXa);
  k_head<<<32, 256, 0, stream>>>(gXa, W4, b4, out);
}

// Round 12
// 118.590 us; speedup vs baseline: 1.1776x; 1.1776x over previous
//
#include <hip/hip_runtime.h>

// B=32, F=node=128, T=2048, HID=256, NC=64, A=15 windows
// Front = R5 shape (k_prep 2196 + k_xw1 256 blocks). k_chain = R11 chain
// (prefetch op1/op2, a3f hoist) + transposed-vectorized adj store.

typedef float f32x4 __attribute__((ext_vector_type(4)));
typedef __bf16 bf16x8 __attribute__((ext_vector_type(8)));
typedef unsigned short u16x4 __attribute__((ext_vector_type(4)));
typedef unsigned short u16x8 __attribute__((ext_vector_type(8)));

__device__ inline unsigned short f2b(float f) {
  unsigned int u = __float_as_uint(f);
  unsigned int r = u + 0x7fffu + ((u >> 16) & 1u);
  return (unsigned short)(r >> 16);
}
__device__ inline float leaky(float v) { return v >= 0.f ? v : 0.2f * v; }

#define SWZ(k, r) ((k) ^ (((r) & 7) << 3))

// ---------------- k_prep: W transposes (bid<148) + x transpose (bid>=148) ----
__global__ __launch_bounds__(256) void k_prep(const float* __restrict__ x,
                                              const float* __restrict__ W1,
                                              const float* __restrict__ W2,
                                              const float* __restrict__ W3,
                                              unsigned short* __restrict__ W1T,
                                              unsigned short* __restrict__ W2T,
                                              unsigned short* __restrict__ W3T,
                                              unsigned short* __restrict__ xT) {
  __shared__ float t[64][65];
  const int bid = blockIdx.x;
  const int tid = threadIdx.x;
  if (bid < 148) {
    const float* src;
    unsigned short* dst;
    int K, N, k0, n0;
    if (bid < 128) {        // W1 [2048][256] -> W1T [256][2048]
      src = W1; dst = W1T; K = 2048; N = 256;
      k0 = (bid >> 2) * 64; n0 = (bid & 3) * 64;
    } else if (bid < 144) { // W2 [256][256] -> W2T [256][256]
      src = W2; dst = W2T; K = 256; N = 256;
      int i = bid - 128; k0 = (i >> 2) * 64; n0 = (i & 3) * 64;
    } else {                // W3 [256][64] -> W3T [64][256]
      src = W3; dst = W3T; K = 256; N = 64;
      int i = bid - 144; k0 = i * 64; n0 = 0;
    }
#pragma unroll
    for (int it = 0; it < 16; ++it) {
      int e = tid + it * 256, r = e >> 6, c = e & 63;
      t[r][c] = src[(size_t)(k0 + r) * N + n0 + c];
    }
    __syncthreads();
#pragma unroll
    for (int it = 0; it < 16; ++it) {
      int e = tid + it * 256, rr = e >> 6, cc = e & 63;
      dst[(size_t)(n0 + rr) * K + k0 + cc] = f2b(t[cc][rr]);
    }
  } else {
    // x [32][128][2048] fp32 -> xT [32][2048][128] bf16, 64x64 tiles
    int idx = bid - 148;               // 0..2047
    int b = idx >> 6, rem = idx & 63;
    int tt = rem >> 1, ft = rem & 1;
    int t0 = tt * 64, f0 = ft * 64;
    const float* xb = x + ((size_t)b * 128 + f0) * 2048 + t0;
#pragma unroll
    for (int it = 0; it < 16; ++it) {
      int e = tid + it * 256, r = e >> 6, c = e & 63;   // r=f-rel, c=t-rel
      t[r][c] = xb[(size_t)r * 2048 + c];
    }
    __syncthreads();
    unsigned short* dst = xT + ((size_t)b * 2048 + t0) * 128 + f0;
#pragma unroll
    for (int it = 0; it < 4; ++it) {
      int e = tid + it * 256, rr = e >> 4, c4 = (e & 15) * 4;  // rr=t-rel, c4=f-rel
      u16x4 s;
#pragma unroll
      for (int q = 0; q < 4; ++q) s[q] = f2b(t[c4 + q][rr]);
      *(u16x4*)&dst[rr * 128 + c4] = s;
    }
  }
}

// ---------------- k_xw1: XW1T[b][hid][f] = (x_b @ W1)^T, 256 blocks ----------------
__global__ __launch_bounds__(512) void k_xw1(const float* __restrict__ x,
                                             const unsigned short* __restrict__ W1T,
                                             unsigned short* __restrict__ XW1T) {
  __shared__ __align__(16) unsigned short sX[2][64 * 64];  // [f][k] bf16 swz, 8KB each
  const int tid = threadIdx.x;
  const int w = tid >> 6, lane = tid & 63;
  const int l15 = lane & 15, l4 = lane >> 4;
  const int bx = blockIdx.x;
  const int hid0 = (bx >> 1) * 64, f0 = (bx & 1) * 64;
  const int b = blockIdx.y;
  const float* xb = x + ((size_t)b * 128 + f0) * 2048;
  const int arow = hid0 + (w & 3) * 16 + l15;   // W1T row for this wave's m-tile
  const int nb = (w >> 2) * 32;                 // f-offset for this wave's 2 n-tiles
  const int fr = tid >> 3, k8 = (tid & 7) * 8;  // staging map

  f32x4 xr0, xr1;
  f32x4 acc[2] = {};

  auto LOADX = [&](int kb) {
    xr0 = *(const f32x4*)&xb[(size_t)fr * 2048 + kb * 64 + k8];
    xr1 = *(const f32x4*)&xb[(size_t)fr * 2048 + kb * 64 + k8 + 4];
  };
  auto STOREX = [&](int buf) {
    u16x8 s;
#pragma unroll
    for (int j = 0; j < 8; ++j) s[j] = f2b(j < 4 ? xr0[j] : xr1[j - 4]);
    *(u16x8*)&sX[buf][fr * 64 + SWZ(k8, fr)] = s;
  };

  LOADX(0);
  STOREX(0);
  __syncthreads();
  for (int kb = 0; kb < 32; ++kb) {
    if (kb < 31) LOADX(kb + 1);
    const int buf = kb & 1;
    bf16x8 af0 = *(const bf16x8*)&W1T[(size_t)arow * 2048 + kb * 64 + l4 * 8];
    bf16x8 af1 = *(const bf16x8*)&W1T[(size_t)arow * 2048 + kb * 64 + 32 + l4 * 8];
#pragma unroll
    for (int nt = 0; nt < 2; ++nt) {
      int br = nb + nt * 16 + l15;
      bf16x8 b0 = *(const bf16x8*)&sX[buf][br * 64 + SWZ(l4 * 8, br)];
      acc[nt] = __builtin_amdgcn_mfma_f32_16x16x32_bf16(af0, b0, acc[nt], 0, 0, 0);
    }
#pragma unroll
    for (int nt = 0; nt < 2; ++nt) {
      int br = nb + nt * 16 + l15;
      bf16x8 b1 = *(const bf16x8*)&sX[buf][br * 64 + SWZ(32 + l4 * 8, br)];
      acc[nt] = __builtin_amdgcn_mfma_f32_16x16x32_bf16(af1, b1, acc[nt], 0, 0, 0);
    }
    if (kb < 31) {
      STOREX(buf ^ 1);
      __syncthreads();
    }
  }
  unsigned short* dst = XW1T + (size_t)b * 256 * 128;
#pragma unroll
  for (int nt = 0; nt < 2; ++nt)
#pragma unroll
    for (int r = 0; r < 4; ++r) {
      int p = hid0 + (w & 3) * 16 + l4 * 4 + r;
      int f = f0 + nb + nt * 16 + l15;
      dst[p * 128 + f] = f2b(acc[nt][r]);
    }
}

// ---------------- k_chain: compact chain + prefetch + vectorized adj store ----------------
__global__ __launch_bounds__(512) void k_chain(
    const unsigned short* __restrict__ xT, const unsigned short* __restrict__ XW1T,
    const unsigned short* __restrict__ W2T, const unsigned short* __restrict__ W3T,
    const float* __restrict__ b1g, const float* __restrict__ b2g,
    const float* __restrict__ b3g, float* __restrict__ gXa) {
  __shared__ __align__(16) unsigned short R0[128 * 128];
  __shared__ __align__(16) unsigned short R1[128 * 128];
  __shared__ float fS[256];

  const int tid = threadIdx.x;
  const int w = tid >> 6, lane = tid & 63;
  const int l15 = lane & 15, l4 = lane >> 4;
  const int ridx = (blockIdx.x & 7) * 60 + (blockIdx.x >> 3);
  const int b = ridx / 15, a = ridx % 15;
  const int m0 = w * 16;
  const unsigned short* XWb = XW1T + (size_t)b * 256 * 128;
  const float inv128 = 1.f / 128.f;

  // ---- P0: win[node j][f] <- xT into R1 ----
  const unsigned short* src = xT + ((size_t)b * 2048 + (size_t)a * 128) * 128;
#pragma unroll 1
  for (int it = 0; it < 4; ++it) {
    int tt = tid + it * 512;
    int j = tt >> 4, f8 = (tt & 15) * 8;
    *(u16x8*)&R1[j * 128 + SWZ(f8, j)] = *(const u16x8*)&src[j * 128 + f8];
  }
  __syncthreads();  // B0

  // ---- syrk prologue: A-frags, row sums (ones-MFMA), own diag (self-MFMA) ----
  bf16x8 afw[4];
#pragma unroll
  for (int ks = 0; ks < 4; ++ks) {
    int ar = m0 + l15;
    afw[ks] = *(const bf16x8*)&R1[ar * 128 + SWZ(ks * 32 + l4 * 8, ar)];
  }
  bf16x8 ones;
#pragma unroll
  for (int q = 0; q < 8; ++q) ones[q] = (__bf16)1.0f;
  f32x4 sacc = {}, dacc = {};
#pragma unroll
  for (int ks = 0; ks < 4; ++ks) {
    sacc = __builtin_amdgcn_mfma_f32_16x16x32_bf16(afw[ks], ones, sacc, 0, 0, 0);
    dacc = __builtin_amdgcn_mfma_f32_16x16x32_bf16(afw[ks], afw[ks], dacc, 0, 0, 0);
  }
#pragma unroll
  for (int r = 0; r < 4; ++r) {
    if (l15 == 0) fS[m0 + l4 * 4 + r] = sacc[r];
    if (l15 == l4 * 4 + r)
      fS[128 + m0 + l4 * 4 + r] = dacc[r] - sacc[r] * sacc[r] * inv128;
  }
  __syncthreads();  // B1: sums + diag visible

  // ---- syrk main: one-pass center/scale/clip -> adj^T(=adj) in R0, ds_write_b64 ----
  float div[4];
#pragma unroll
  for (int r = 0; r < 4; ++r) {
    float d = fS[128 + m0 + l4 * 4 + r];
    div[r] = d > 0.f ? __frsqrt_rn(d) : 0.f;
  }
#pragma unroll 1
  for (int nt = 0; nt < 8; ++nt) {
    int col = nt * 16 + l15;
    f32x4 c = {};
#pragma unroll
    for (int ks = 0; ks < 4; ++ks) {
      bf16x8 bf = *(const bf16x8*)&R1[col * 128 + SWZ(ks * 32 + l4 * 8, col)];
      c = __builtin_amdgcn_mfma_f32_16x16x32_bf16(afw[ks], bf, c, 0, 0, 0);
    }
    float fc = fS[col];
    float dc = fS[128 + col];
    float djv = dc > 0.f ? __frsqrt_rn(dc) : 0.f;
    u16x4 pk;
#pragma unroll
    for (int r = 0; r < 4; ++r) {
      float v = (c[r] - sacc[r] * fc * inv128) * div[r] * djv;
      v = fminf(1.f, fmaxf(-1.f, v));
      v = 0.5f * v + 0.5f;
      if (div[r] == 0.f || djv == 0.f) v = 0.f;  // nan_to_num
      pk[r] = f2b(v);
    }
    // transposed store (adj symmetric): row = col-index, 4 contiguous m-cols
    *(u16x4*)&R0[col * 128 + SWZ(m0 + l4 * 4, col)] = pk;
  }
  __syncthreads();  // B2: adj complete (all waves contribute to every row)

  bf16x8 afj[4];
#pragma unroll
  for (int ks = 0; ks < 4; ++ks)
    afj[ks] = *(const bf16x8*)&R0[(m0 + l15) * 128 + SWZ(ks * 32 + l4 * 8, m0 + l15)];
  // afj reads are this wave's own program-order LDS reads; op1's first R1 writes
  // target this wave's own rows (win fully consumed by all waves before B2).

  // ---- op1: h1 = leaky(adj @ XW1b + b1); B prefetched 1 nt ahead ----
#pragma unroll 1
  for (int half = 0; half < 2; ++half) {
    unsigned short* Rd = half ? R0 : R1;
    const unsigned short* Bbase = &XWb[(size_t)half * 128 * 128 + l4 * 8];
    bf16x8 bpf[4];
#pragma unroll
    for (int ks = 0; ks < 4; ++ks)
      bpf[ks] = *(const bf16x8*)&Bbase[(size_t)l15 * 128 + ks * 32];
#pragma unroll 1
    for (int nt = 0; nt < 8; ++nt) {
      bf16x8 bc[4];
#pragma unroll
      for (int ks = 0; ks < 4; ++ks) bc[ks] = bpf[ks];
      if (nt < 7) {
#pragma unroll
        for (int ks = 0; ks < 4; ++ks)
          bpf[ks] = *(const bf16x8*)&Bbase[(size_t)((nt + 1) * 16 + l15) * 128 + ks * 32];
      }
      f32x4 acc = {};
#pragma unroll
      for (int ks = 0; ks < 4; ++ks)
        acc = __builtin_amdgcn_mfma_f32_16x16x32_bf16(afj[ks], bc[ks], acc, 0, 0, 0);
      float bias = b1g[half * 128 + nt * 16 + l15];
#pragma unroll
      for (int r = 0; r < 4; ++r) {
        int row = m0 + l4 * 4 + r;
        Rd[row * 128 + SWZ(nt * 16 + l15, row)] = f2b(leaky(acc[r] + bias));
      }
    }
  }
  __syncthreads();  // B3: h1 complete

  // ---- op2: u2T = W2T @ h1^T, K=256; A prefetched 1 ks ahead ----
  f32x4 u2[2][8] = {};
  {
    const unsigned short* A0 = &W2T[(size_t)(w * 32 + l15) * 256 + l4 * 8];
    const unsigned short* A1 = &W2T[(size_t)(w * 32 + 16 + l15) * 256 + l4 * 8];
    bf16x8 a0p = *(const bf16x8*)&A0[0];
    bf16x8 a1p = *(const bf16x8*)&A1[0];
#pragma unroll 1
    for (int ks = 0; ks < 8; ++ks) {
      bf16x8 a0 = a0p, a1 = a1p;
      if (ks < 7) {
        a0p = *(const bf16x8*)&A0[(ks + 1) * 32];
        a1p = *(const bf16x8*)&A1[(ks + 1) * 32];
      }
      const unsigned short* Rs = (ks < 4) ? R1 : R0;
      int kk = (ks & 3) * 32 + l4 * 8;
#pragma unroll
      for (int nt = 0; nt < 8; ++nt) {
        int br = nt * 16 + l15;
        bf16x8 bf = *(const bf16x8*)&Rs[br * 128 + SWZ(kk, br)];
        u2[0][nt] = __builtin_amdgcn_mfma_f32_16x16x32_bf16(a0, bf, u2[0][nt], 0, 0, 0);
        u2[1][nt] = __builtin_amdgcn_mfma_f32_16x16x32_bf16(a1, bf, u2[1][nt], 0, 0, 0);
      }
    }
  }
  __syncthreads();  // B4: all h1 reads done

#pragma unroll
  for (int mt = 0; mt < 2; ++mt)
#pragma unroll
    for (int nt = 0; nt < 8; ++nt)
#pragma unroll
      for (int r = 0; r < 4; ++r) {
        int grow = w * 32 + mt * 16 + l4 * 4 + r;
        int col = nt * 16 + l15;
        unsigned short* Rd = (grow < 128) ? R0 : R1;
        int lr = grow & 127;
        Rd[lr * 128 + SWZ(col, lr)] = f2b(u2[mt][nt][r]);
      }
  __syncthreads();  // B5: u2T stored

  // ---- op3: h2 = leaky(adj @ u2 + b2), full hid 256 ----
  f32x4 h2acc[16];
#pragma unroll
  for (int nt = 0; nt < 16; ++nt) h2acc[nt] = f32x4{0.f, 0.f, 0.f, 0.f};
#pragma unroll
  for (int ks = 0; ks < 4; ++ks)
#pragma unroll
    for (int nt = 0; nt < 16; ++nt) {
      int brl = (nt & 7) * 16 + l15;
      const unsigned short* Rs = (nt < 8) ? R0 : R1;
      bf16x8 bf = *(const bf16x8*)&Rs[brl * 128 + SWZ(ks * 32 + l4 * 8, brl)];
      h2acc[nt] = __builtin_amdgcn_mfma_f32_16x16x32_bf16(afj[ks], bf, h2acc[nt], 0, 0, 0);
    }
  __syncthreads();  // B6: all u2T reads done

#pragma unroll
  for (int nt = 0; nt < 16; ++nt) {
    float bias = b2g[nt * 16 + l15];
#pragma unroll
    for (int r = 0; r < 4; ++r) {
      int row = m0 + l4 * 4 + r;
      int coll = (nt & 7) * 16 + l15;
      unsigned short* Rd = (nt < 8) ? R0 : R1;
      Rd[row * 128 + SWZ(coll, row)] = f2b(leaky(h2acc[nt][r] + bias));
    }
  }
  // ---- hoist op4 A-frags (W3T): latency hides under B7 + op4 B-reads ----
  const int mrow = (w >> 1) * 16, ntb = (w & 1) * 4;
  bf16x8 a3f[8];
#pragma unroll
  for (int ks = 0; ks < 8; ++ks)
    a3f[ks] = *(const bf16x8*)&W3T[(size_t)(mrow + l15) * 256 + ks * 32 + l4 * 8];
  __syncthreads();  // B7: h2 stored

  // ---- op4: u3T = W3T @ h2^T, K=256 (R0 then R1) ----
  f32x4 u3[4] = {};
#pragma unroll
  for (int kh = 0; kh < 2; ++kh) {
    const unsigned short* Rs = kh ? R1 : R0;
#pragma unroll
    for (int ks = 0; ks < 4; ++ks) {
#pragma unroll
      for (int nti = 0; nti < 4; ++nti) {
        int br = (ntb + nti) * 16 + l15;
        bf16x8 bf = *(const bf16x8*)&Rs[br * 128 + SWZ(ks * 32 + l4 * 8, br)];
        u3[nti] = __builtin_amdgcn_mfma_f32_16x16x32_bf16(a3f[kh * 4 + ks], bf, u3[nti], 0, 0, 0);
      }
    }
  }
  __syncthreads();  // B8: all h2 reads done

#pragma unroll
  for (int nti = 0; nti < 4; ++nti)
#pragma unroll
    for (int r = 0; r < 4; ++r) {
      int grow = mrow + l4 * 4 + r;
      int col = (ntb + nti) * 16 + l15;
      R0[grow * 128 + SWZ(col, grow)] = f2b(u3[nti][r]);
    }
  __syncthreads();  // B9: u3T stored

  // ---- op5: xa = leaky(adj @ u3 + b3); mean over node via shuffles ----
  {
    float* pf = reinterpret_cast<float*>(R1);
#pragma unroll 1
    for (int nt = 0; nt < 4; ++nt) {
      f32x4 acc = {};
      int br = nt * 16 + l15;
#pragma unroll
      for (int ks = 0; ks < 4; ++ks) {
        bf16x8 bf = *(const bf16x8*)&R0[br * 128 + SWZ(ks * 32 + l4 * 8, br)];
        acc = __builtin_amdgcn_mfma_f32_16x16x32_bf16(afj[ks], bf, acc, 0, 0, 0);
      }
      float bias = b3g[br];
      float v = 0.f;
#pragma unroll
      for (int r = 0; r < 4; ++r) v += leaky(acc[r] + bias);
      v += __shfl_xor(v, 16);
      v += __shfl_xor(v, 32);
      if (l4 == 0) pf[w * 64 + br] = v;
    }
  }
  __syncthreads();  // B10
  if (tid < 64) {
    const float* pf = reinterpret_cast<const float*>(R1);
    float s = 0.f;
#pragma unroll
    for (int gg = 0; gg < 8; ++gg) s += pf[gg * 64 + tid];
    gXa[((size_t)b * 15 + a) * 64 + tid] = s * (1.f / 128.f);
  }
}

// ---------------- k_head: per-batch head ----------------
__global__ __launch_bounds__(256) void k_head(const float* __restrict__ gXa,
                                              const float* __restrict__ W4,
                                              const float* __restrict__ b4,
                                              float* __restrict__ out) {
  __shared__ float xb[15 * 64];
  __shared__ float c2[15 * 16];
  __shared__ float mu[15];
  __shared__ float dinv[15];
  __shared__ float yy[15 * 64];
  __shared__ float zz[15 * 64];
  const int b = blockIdx.x;
  const int tid = threadIdx.x;
  for (int e = tid; e < 960; e += 256) xb[e] = gXa[(size_t)b * 960 + e];
  __syncthreads();
  if (tid < 15) {
    float s = 0.f;
    for (int c = 0; c < 64; ++c) s += xb[tid * 64 + c];
    mu[tid] = s * (1.f / 64.f);
  }
  __syncthreads();
  if (tid < 225) {
    int p = tid / 15, q = tid % 15;
    float s = 0.f;
    for (int c = 0; c < 64; ++c)
      s += (xb[p * 64 + c] - mu[p]) * (xb[q * 64 + c] - mu[q]);
    c2[p * 16 + q] = s;
  }
  __syncthreads();
  if (tid < 15) {
    float d = c2[tid * 16 + tid];
    dinv[tid] = d > 0.f ? (1.f / sqrtf(d)) : 0.f;
  }
  __syncthreads();
  if (tid < 225) {
    int p = tid / 15, q = tid % 15;
    float v = c2[p * 16 + q] * dinv[p] * dinv[q];
    v = fminf(1.f, fmaxf(-1.f, v));
    if (dinv[p] == 0.f || dinv[q] == 0.f) v = 0.f;
    c2[p * 16 + q] = v;
  }
  __syncthreads();
  for (int e = tid; e < 960; e += 256) {
    int p = e >> 6, c = e & 63;
    float s = 0.f;
    for (int q = 0; q < 15; ++q) s += c2[p * 16 + q] * xb[q * 64 + c];
    yy[e] = s;
  }
  __syncthreads();
  for (int e = tid; e < 960; e += 256) {
    int p = e >> 6, c = e & 63;
    float s = b4[c];
    for (int k = 0; k < 64; ++k) s += yy[p * 64 + k] * W4[k * 64 + c];
    zz[e] = leaky(s);
  }
  __syncthreads();
  if (tid < 64) {
    float m = -INFINITY;
    for (int p = 0; p < 15; ++p) m = fmaxf(m, zz[p * 64 + tid]);
    out[(size_t)b * 64 + tid] = m;
  }
}

extern "C" void kernel_launch(void* const* d_in, const int* in_sizes, int n_in,
                              void* d_out, int out_size, void* d_ws, size_t ws_size,
                              hipStream_t stream) {
  const float* x  = (const float*)d_in[0];
  const float* W1 = (const float*)d_in[1];
  const float* b1 = (const float*)d_in[2];
  const float* W2 = (const float*)d_in[3];
  const float* b2 = (const float*)d_in[4];
  const float* W3 = (const float*)d_in[5];
  const float* b3 = (const float*)d_in[6];
  const float* W4 = (const float*)d_in[7];
  const float* b4 = (const float*)d_in[8];
  float* out = (float*)d_out;

  char* ws = (char*)d_ws;
  unsigned short* xT   = (unsigned short*)ws;                 // 16 MB
  unsigned short* XW1T = (unsigned short*)(ws + 16777216);    // 2 MB
  unsigned short* W1T  = (unsigned short*)(ws + 18874368);    // 1 MB
  unsigned short* W2T  = (unsigned short*)(ws + 19922944);    // 128 KB
  unsigned short* W3T  = (unsigned short*)(ws + 20054016);    // 32 KB
  float* gXa           = (float*)(ws + 20086784);             // 120 KB

  k_prep<<<2196, 256, 0, stream>>>(x, W1, W2, W3, W1T, W2T, W3T, xT);
  dim3 gx(8, 32);
  k_xw1<<<gx, 512, 0, stream>>>(x, W1T, XW1T);
  k_chain<<<480, 512, 0, stream>>>(xT, XW1T, W2T, W3T, b1, b2, b3, gXa);
  k_head<<<32, 256, 0, stream>>>(gXa, W4, b4, out);
}